// Round 19
// baseline (439.050 us; speedup 1.0000x reference)
//
#include <hip/hip_runtime.h>
#include <hip/hip_bf16.h>

#define NN 50000
#define NE 800000
#define NB ((NN + 1023) / 1024)

typedef __attribute__((ext_vector_type(8))) short short8;
typedef __attribute__((ext_vector_type(4))) float f32x4;

#define AS1 __attribute__((address_space(1)))
#define AS3 __attribute__((address_space(3)))

__device__ inline float bf2f(unsigned short u) {
    unsigned v = (unsigned)u << 16;
    return __builtin_bit_cast(float, v);
}
__device__ inline unsigned short f2bf(float f) {
    return __builtin_bit_cast(unsigned short, __float2bfloat16(f));
}

// ---------------- prep: zero cnt/stats, x->bf16, pack weights (one launch) ----------------
__device__ inline void packw_dev(const float* __restrict__ Wl, const float* __restrict__ Wr,
                                 unsigned short* __restrict__ Wb, int C, int idx) {
    int K = 2 * C;
    if (idx >= 256 * K) return;
    int n = idx / K, k = idx % K;
    float v = (k < C) ? Wl[n * C + k] : Wr[n * C + (k - C)];
    Wb[idx] = f2bf(v);
}

__global__ __launch_bounds__(256) void k_prep(const float* __restrict__ x,
                                              const float* __restrict__ Wl0, const float* __restrict__ Wr0,
                                              const float* __restrict__ Wl1, const float* __restrict__ Wr1,
                                              const float* __restrict__ Wl2, const float* __restrict__ Wr2,
                                              unsigned short* __restrict__ F0,
                                              unsigned short* __restrict__ Wb0,
                                              unsigned short* __restrict__ Wb1,
                                              unsigned short* __restrict__ Wb2,
                                              int* __restrict__ cnt, float* __restrict__ stats) {
    int b = blockIdx.x, t = threadIdx.x;
    if (b < 6250) {  // x fp32 [NN][128] -> F0[:,128:256] bf16
        int i = b * 256 + t;
        if (i < NN * 32) {
            int row = i >> 5, c4 = (i & 31) * 4;
            float4 v = reinterpret_cast<const float4*>(x)[i];
            ushort4 o;
            o.x = f2bf(v.x); o.y = f2bf(v.y); o.z = f2bf(v.z); o.w = f2bf(v.w);
            *reinterpret_cast<ushort4*>(F0 + (size_t)row * 256 + 128 + c4) = o;
        }
        return;
    }
    b -= 6250;
    if (b < 256) { packw_dev(Wl0, Wr0, Wb0, 128, b * 256 + t); return; }
    b -= 256;
    if (b < 512) { packw_dev(Wl1, Wr1, Wb1, 256, b * 256 + t); return; }
    b -= 512;
    if (b < 512) { packw_dev(Wl2, Wr2, Wb2, 256, b * 256 + t); return; }
    b -= 512;
    if (b < 196) { int i = b * 256 + t; if (i < NN) cnt[i] = 0; return; }
    b -= 196;
    if (b < 6) { int i = b * 256 + t; if (i < 1536) stats[i] = 0.f; return; }
}
#define PREP_BLOCKS (6250 + 256 + 512 + 512 + 196 + 6)

// ---------------- CSR build ----------------
__global__ __launch_bounds__(256) void k_count(const int* __restrict__ dst, int* __restrict__ cnt) {
    int e = blockIdx.x * 256 + threadIdx.x;
    if (e < NE) atomicAdd(&cnt[dst[e]], 1);
}

__global__ __launch_bounds__(1024) void k_scanA(const int* __restrict__ cnt, int* __restrict__ row_start,
                                                int* __restrict__ bsum) {
    __shared__ int wsum[16];
    int t = threadIdx.x, lane = t & 63, wid = t >> 6;
    int i = blockIdx.x * 1024 + t;
    int v = (i < NN) ? cnt[i] : 0;
    int x = v;
    #pragma unroll
    for (int off = 1; off < 64; off <<= 1) {
        int y = __shfl_up(x, off, 64);
        if (lane >= off) x += y;
    }
    if (lane == 63) wsum[wid] = x;
    __syncthreads();
    if (t < 16) {
        int s = wsum[t];
        #pragma unroll
        for (int off = 1; off < 16; off <<= 1) {
            int y = __shfl_up(s, off, 16);
            if (t >= off) s += y;
        }
        wsum[t] = s;
    }
    __syncthreads();
    int pre = wid ? wsum[wid - 1] : 0;
    if (i < NN) row_start[i] = pre + x - v;
    if (t == 0) bsum[blockIdx.x] = wsum[15];
}

__global__ __launch_bounds__(64) void k_scanB(const int* __restrict__ bsum, int* __restrict__ boff,
                                              int* __restrict__ row_start) {
    int l = threadIdx.x;
    int v = (l < NB) ? bsum[l] : 0;
    int x = v;
    #pragma unroll
    for (int off = 1; off < 64; off <<= 1) {
        int y = __shfl_up(x, off, 64);
        if (l >= off) x += y;
    }
    boff[l] = x - v;
    if (l == 63) row_start[NN] = x;
}

__global__ __launch_bounds__(1024) void k_scanC(int* __restrict__ row_start, const int* __restrict__ boff,
                                                int* __restrict__ cursor) {
    int i = blockIdx.x * 1024 + threadIdx.x;
    if (i < NN) {
        int rs = row_start[i] + boff[blockIdx.x];
        row_start[i] = rs;
        cursor[i] = rs;
    }
}

__global__ __launch_bounds__(256) void k_scatter(const int* __restrict__ src, const int* __restrict__ dst,
                                                 int* __restrict__ cursor, int* __restrict__ col) {
    int e = blockIdx.x * 256 + threadIdx.x;
    if (e >= NE) return;
    int d = dst[e];
    int p = atomicAdd(&cursor[d], 1);
    col[p] = src[e];
}

// ---------------- mean aggregation: unroll 8, reads F[:,C:], writes F[:,:C] ----------------
template <int C, int S>
__global__ __launch_bounds__(256) void k_agg3(unsigned short* __restrict__ F,
                                              const int* __restrict__ row_start,
                                              const int* __restrict__ col) {
    constexpr int LPN = C / 8;       // lanes per node
    constexpr int NPB = 256 / LPN;   // nodes per block
    int l = threadIdx.x & (LPN - 1);
    int n = blockIdx.x * NPB + (threadIdx.x / LPN);
    if (n >= NN) return;
    int beg = row_start[n], end = row_start[n + 1];
    float inv = 1.0f / (float)((end - beg) > 1 ? (end - beg) : 1);
    float a[8] = {0.f, 0.f, 0.f, 0.f, 0.f, 0.f, 0.f, 0.f};
    const unsigned short* hp = F + C + l * 8;  // h half
    for (int base = beg; base < end; base += LPN) {
        int idx = base + l;
        int my = (idx < end) ? col[idx] : 0;
        int cnt = end - base; if (cnt > LPN) cnt = LPN;
        int j = 0;
        for (; j + 8 <= cnt; j += 8) {
            int s[8];
            #pragma unroll
            for (int q = 0; q < 8; ++q) s[q] = __shfl(my, j + q, LPN);
            short8 v[8];
            #pragma unroll
            for (int q = 0; q < 8; ++q) v[q] = *reinterpret_cast<const short8*>(hp + (size_t)s[q] * S);
            #pragma unroll
            for (int q = 0; q < 8; ++q)
                #pragma unroll
                for (int k = 0; k < 8; ++k) a[k] += bf2f((unsigned short)v[q][k]);
        }
        for (; j + 4 <= cnt; j += 4) {
            int s0 = __shfl(my, j + 0, LPN);
            int s1 = __shfl(my, j + 1, LPN);
            int s2 = __shfl(my, j + 2, LPN);
            int s3 = __shfl(my, j + 3, LPN);
            short8 v0 = *reinterpret_cast<const short8*>(hp + (size_t)s0 * S);
            short8 v1 = *reinterpret_cast<const short8*>(hp + (size_t)s1 * S);
            short8 v2 = *reinterpret_cast<const short8*>(hp + (size_t)s2 * S);
            short8 v3 = *reinterpret_cast<const short8*>(hp + (size_t)s3 * S);
            #pragma unroll
            for (int k = 0; k < 8; ++k) {
                a[k] += bf2f((unsigned short)v0[k]);
                a[k] += bf2f((unsigned short)v1[k]);
                a[k] += bf2f((unsigned short)v2[k]);
                a[k] += bf2f((unsigned short)v3[k]);
            }
        }
        for (; j < cnt; ++j) {
            int s = __shfl(my, j, LPN);
            short8 v = *reinterpret_cast<const short8*>(hp + (size_t)s * S);
            #pragma unroll
            for (int k = 0; k < 8; ++k) a[k] += bf2f((unsigned short)v[k]);
        }
    }
    unsigned short o[8];
    #pragma unroll
    for (int k = 0; k < 8; ++k) o[k] = f2bf(a[k] * inv);
    *reinterpret_cast<short8*>(F + (size_t)n * S + l * 8) = *reinterpret_cast<short8*>(o);
}

// ---------------- barrier-free MFMA GEMM, 32-col B tiles for occupancy ----------------
// vs R13/R18: B panel halved to 32 cols -> LDS 32 KB (K=512) / 16 KB (K=256); grid 832
// (104 stripes x 8 tiles, XCD-affine); per-wave acc[4][2]. Wave capacity 2->3-4 blocks/CU
// (the 16-24% OccupancyPercent across all prior 64KB-LDS variants was the common limiter).
template <int K>
__global__ __launch_bounds__(512) void k_gemm11(const unsigned short* __restrict__ F,  // [NN][K]
                                                const unsigned short* __restrict__ Wb, // [256][K]
                                                unsigned short* __restrict__ zb, int ZS, int zoff,
                                                float* __restrict__ st) {
    constexpr int T = K / 32;        // K-steps
    constexpr int SL = K / 8;        // 16B slots per col
    constexpr int LOG_SL = (K == 512) ? 6 : 5;
    __shared__ __attribute__((aligned(16))) unsigned short sB[32 * K];  // 32 KB (K=512) / 16 KB

    // XCD-affine remap: bid in [0,832); hw XCD = bid%8. All 8 tiles of a stripe share an XCD.
    int bid = blockIdx.x;
    int xcd = bid & 7, j = bid >> 3;       // j in [0,104)
    int tile = j & 7;                      // 8 tiles of 32 cols
    int stripe = (j >> 3) * 8 + xcd;       // [0,104)
    if (stripe * 512 >= NN) return;        // dead stripes 98..103

    int tid = threadIdx.x;
    int lane = tid & 63, w = tid >> 6;
    int colB = tile * 32;
    int row0 = stripe * 512 + w * 64;
    int rl = lane & 15, kh = lane >> 4;

    // ---- stage B panel once (XOR-swizzled; linear LDS dest, pre-swizzled source)
    #pragma unroll
    for (int rnd = 0; rnd < (32 * SL) / 512; ++rnd) {
        int u = rnd * 512 + tid;
        int bcol = u >> LOG_SL, s = u & (SL - 1);
        int gk = (s ^ (bcol & 15)) * 8;
        __builtin_amdgcn_global_load_lds((const AS1 void*)(Wb + (size_t)(colB + bcol) * K + gk),
                                         (AS3 void*)(sB + (size_t)(rnd * 512 + w * 64) * 8), 16, 0, 0);
    }
    __syncthreads();  // drains vmcnt to 0 -> ring counting below is exact

    // ---- A row pointers (clamped; clamped rows skipped in epilogue)
    const unsigned short* ap[4];
    #pragma unroll
    for (int m = 0; m < 4; ++m) {
        int r = row0 + m * 16 + rl;
        if (r >= NN) r = NN - 1;
        ap[m] = F + (size_t)r * K + kh * 8;
    }

    f32x4 acc[4][2] = {};
    short8 ring[4][4];  // asm-pinned depth-4 prefetch ring; indices compile-time after unroll

    // prologue: 16 loads in flight (oldest-first order matters for vmcnt counting)
    #pragma unroll
    for (int d = 0; d < 4; ++d)
        #pragma unroll
        for (int m = 0; m < 4; ++m)
            asm volatile("global_load_dwordx4 %0, %1, off"
                         : "=v"(ring[d][m]) : "v"(ap[m] + d * 32));

    #pragma unroll
    for (int t = 0; t < T; ++t) {
        // wait for ring slot t (oldest 4); keep up to 12 newer loads in flight
        if (t + 3 < T)      asm volatile("s_waitcnt vmcnt(12)");
        else if (t + 2 < T) asm volatile("s_waitcnt vmcnt(8)");
        else if (t + 1 < T) asm volatile("s_waitcnt vmcnt(4)");
        else                asm volatile("s_waitcnt vmcnt(0)");
        __builtin_amdgcn_sched_barrier(0);  // rule #18: keep MFMA below the wait

        short8 bf[2];
        int kc = t * 4 + kh;
        #pragma unroll
        for (int n = 0; n < 2; ++n) {
            int c = n * 16 + rl;  // local col in [0,32)
            int unit = (c << LOG_SL) + (kc ^ (c & 15));
            bf[n] = *reinterpret_cast<const short8*>(sB + (size_t)unit * 8);
        }
        __builtin_amdgcn_s_setprio(1);
        #pragma unroll
        for (int m = 0; m < 4; ++m)
            #pragma unroll
            for (int n = 0; n < 2; ++n)
                acc[m][n] = __builtin_amdgcn_mfma_f32_16x16x32_bf16(ring[t % 4][m], bf[n],
                                                                    acc[m][n], 0, 0, 0);
        __builtin_amdgcn_s_setprio(0);
        if (t + 4 < T) {
            #pragma unroll
            for (int m = 0; m < 4; ++m)
                asm volatile("global_load_dwordx4 %0, %1, off"
                             : "=v"(ring[t % 4][m]) : "v"(ap[m] + (t + 4) * 32));
        }
    }

    // ---- epilogue: bf16 store + per-column BN partial sums (fp32)
    int cbase = lane & 15;
    int rbase = (lane >> 4) * 4;
    float s1[2] = {0.f, 0.f};
    float s2[2] = {0.f, 0.f};
    #pragma unroll
    for (int m = 0; m < 4; ++m) {
        #pragma unroll
        for (int jj = 0; jj < 4; ++jj) {
            int r = row0 + m * 16 + rbase + jj;
            if (r < NN) {
                #pragma unroll
                for (int n = 0; n < 2; ++n) {
                    float v = acc[m][n][jj];
                    zb[(size_t)r * ZS + zoff + colB + n * 16 + cbase] = f2bf(v);
                    s1[n] += v;
                    s2[n] += v * v;
                }
            }
        }
    }
    // within-wave fold (lanes with same cbase)
    #pragma unroll
    for (int n = 0; n < 2; ++n) {
        s1[n] += __shfl_xor(s1[n], 16);
        s1[n] += __shfl_xor(s1[n], 32);
        s2[n] += __shfl_xor(s2[n], 16);
        s2[n] += __shfl_xor(s2[n], 32);
    }
    // cross-wave fold in LDS (alias sB; all B reads are done), then 1 atomic/address/block
    __syncthreads();
    float* red = (float*)sB;  // 512 floats = 2 KB << sizeof(sB)
    if (lane < 16) {
        #pragma unroll
        for (int n = 0; n < 2; ++n) {
            red[(w * 2 + n) * 16 + lane] = s1[n];
            red[256 + (w * 2 + n) * 16 + lane] = s2[n];
        }
    }
    __syncthreads();
    if (tid < 64) {
        int stat = tid >> 5, idx = tid & 31;
        int n = idx >> 4, l16 = idx & 15;
        float s = 0.f;
        #pragma unroll
        for (int w2 = 0; w2 < 8; ++w2) s += red[stat * 256 + (w2 * 2 + n) * 16 + l16];
        atomicAdd(&st[stat * 256 + colB + n * 16 + l16], s);
    }
}

// ---------------- BatchNorm apply (BN params computed per-block from stats) ----------------
// in-place BN+ReLU on bf16 z stored at F[:,256:512]
__global__ __launch_bounds__(256) void k_bnip2(unsigned short* __restrict__ F1,
                                               const float* __restrict__ st,
                                               const float* __restrict__ g,
                                               const float* __restrict__ b) {
    __shared__ float ssc[256], ssh[256];
    int t = threadIdx.x;
    {
        float mu = st[t] * (1.0f / NN);
        float var = st[256 + t] * (1.0f / NN) - mu * mu;
        float rstd = rsqrtf(fmaxf(var, 0.f) + 1e-5f);
        float sc = g[t] * rstd;
        ssc[t] = sc;
        ssh[t] = b[t] - mu * sc;
    }
    __syncthreads();
    int i = blockIdx.x * 256 + t;  // NN*64 ushort4 units
    if (i >= NN * 64) return;
    int row = i >> 6, c4 = (i & 63) * 4;
    unsigned short* p = F1 + (size_t)row * 512 + 256 + c4;
    ushort4 v = *reinterpret_cast<const ushort4*>(p);
    float4 sc = *reinterpret_cast<const float4*>(&ssc[c4]);
    float4 sh = *reinterpret_cast<const float4*>(&ssh[c4]);
    ushort4 o;
    o.x = f2bf(fmaxf(bf2f(v.x) * sc.x + sh.x, 0.f));
    o.y = f2bf(fmaxf(bf2f(v.y) * sc.y + sh.y, 0.f));
    o.z = f2bf(fmaxf(bf2f(v.z) * sc.z + sh.z, 0.f));
    o.w = f2bf(fmaxf(bf2f(v.w) * sc.w + sh.w, 0.f));
    *reinterpret_cast<ushort4*>(p) = o;
}

// final BN (no ReLU): bf16 z at F[:,256:512] -> fp32 out
__global__ __launch_bounds__(256) void k_bnf2(const unsigned short* __restrict__ F,
                                              const float* __restrict__ st,
                                              const float* __restrict__ g,
                                              const float* __restrict__ b,
                                              float* __restrict__ out) {
    __shared__ float ssc[256], ssh[256];
    int t = threadIdx.x;
    {
        float mu = st[t] * (1.0f / NN);
        float var = st[256 + t] * (1.0f / NN) - mu * mu;
        float rstd = rsqrtf(fmaxf(var, 0.f) + 1e-5f);
        float sc = g[t] * rstd;
        ssc[t] = sc;
        ssh[t] = b[t] - mu * sc;
    }
    __syncthreads();
    int i = blockIdx.x * 256 + t;
    if (i >= NN * 64) return;
    int row = i >> 6, c4 = (i & 63) * 4;
    ushort4 v = *reinterpret_cast<const ushort4*>(F + (size_t)row * 512 + 256 + c4);
    float4 sc = *reinterpret_cast<const float4*>(&ssc[c4]);
    float4 sh = *reinterpret_cast<const float4*>(&ssh[c4]);
    float4 o;
    o.x = bf2f(v.x) * sc.x + sh.x;
    o.y = bf2f(v.y) * sc.y + sh.y;
    o.z = bf2f(v.z) * sc.z + sh.z;
    o.w = bf2f(v.w) * sc.w + sh.w;
    reinterpret_cast<float4*>(out)[i] = o;
}

extern "C" void kernel_launch(void* const* d_in, const int* in_sizes, int n_in,
                              void* d_out, int out_size, void* d_ws, size_t ws_size,
                              hipStream_t stream) {
    const float* x   = (const float*)d_in[0];
    const int*   ei  = (const int*)d_in[1];
    const float* Wl0 = (const float*)d_in[2];
    const float* Wr0 = (const float*)d_in[4];
    const float* g0  = (const float*)d_in[5];
    const float* b0  = (const float*)d_in[6];
    const float* Wl1 = (const float*)d_in[7];
    const float* Wr1 = (const float*)d_in[9];
    const float* g1  = (const float*)d_in[10];
    const float* b1  = (const float*)d_in[11];
    const float* Wl2 = (const float*)d_in[12];
    const float* Wr2 = (const float*)d_in[14];
    const float* g2  = (const float*)d_in[15];
    const float* b2  = (const float*)d_in[16];
    float* out = (float*)d_out;

    char* ws = (char*)d_ws;
    size_t off = 0;
    auto alloc = [&](size_t bytes) -> void* {
        void* p = ws + off;
        off = (off + bytes + 255) & ~(size_t)255;
        return p;
    };
    unsigned short* F0 = (unsigned short*)alloc((size_t)NN * 256 * 2);  // layer0 [mean0|x]
    unsigned short* FA = (unsigned short*)alloc((size_t)NN * 512 * 2);  // ping [mean|h]
    unsigned short* FB = (unsigned short*)alloc((size_t)NN * 512 * 2);  // pong [mean|h]
    int*   cnt       = (int*)alloc((size_t)NN * 4);
    int*   cursor    = (int*)alloc((size_t)NN * 4);
    int*   row_start = (int*)alloc((size_t)(NN + 1) * 4);
    int*   col       = (int*)alloc((size_t)NE * 4);
    int*   bsum      = (int*)alloc(64 * 4);
    int*   boff      = (int*)alloc(64 * 4);
    float* stats     = (float*)alloc(3 * 512 * 4);
    unsigned short* Wb0 = (unsigned short*)alloc((size_t)256 * 256 * 2);
    unsigned short* Wb1 = (unsigned short*)alloc((size_t)256 * 512 * 2);
    unsigned short* Wb2 = (unsigned short*)alloc((size_t)256 * 512 * 2);

    // prep (zero cnt/stats, convert x, pack weights) + CSR build
    k_prep<<<PREP_BLOCKS, 256, 0, stream>>>(x, Wl0, Wr0, Wl1, Wr1, Wl2, Wr2,
                                            F0, Wb0, Wb1, Wb2, cnt, stats);
    k_count<<<(NE + 255) / 256, 256, 0, stream>>>(ei + NE, cnt);
    k_scanA<<<NB, 1024, 0, stream>>>(cnt, row_start, bsum);
    k_scanB<<<1, 64, 0, stream>>>(bsum, boff, row_start);
    k_scanC<<<NB, 1024, 0, stream>>>(row_start, boff, cursor);
    k_scatter<<<(NE + 255) / 256, 256, 0, stream>>>(ei, ei + NE, cursor, col);

    const int GGRID = 832;  // 104 stripes x 8 tiles of 32 cols, XCD-affine

    // ---- Layer 0 (C=128, K=256): F0 -> z0 in FA[:,256:] ----
    k_agg3<128, 256><<<(NN + 15) / 16, 256, 0, stream>>>(F0, row_start, col);
    k_gemm11<256><<<GGRID, 512, 0, stream>>>(F0, Wb0, FA, 512, 256, stats);
    k_bnip2<<<12500, 256, 0, stream>>>(FA, stats, g0, b0);

    // ---- Layer 1 (C=256, K=512): FA -> z1 in FB[:,256:] (out-of-place) ----
    k_agg3<256, 512><<<(NN + 7) / 8, 256, 0, stream>>>(FA, row_start, col);
    k_gemm11<512><<<GGRID, 512, 0, stream>>>(FA, Wb1, FB, 512, 256, stats + 512);
    k_bnip2<<<12500, 256, 0, stream>>>(FB, stats + 512, g1, b1);

    // ---- Layer 2 (C=256, K=512): FB -> z2 in FA[:,256:] (FA dead, out-of-place) ----
    k_agg3<256, 512><<<(NN + 7) / 8, 256, 0, stream>>>(FB, row_start, col);
    k_gemm11<512><<<GGRID, 512, 0, stream>>>(FB, Wb2, FA, 512, 256, stats + 1024);
    k_bnf2<<<12500, 256, 0, stream>>>(FA, stats + 1024, g2, b2, out);
}

// Round 20
// 377.522 us; speedup vs baseline: 1.1630x; 1.1630x over previous
//
#include <hip/hip_runtime.h>
#include <hip/hip_bf16.h>

#define NN 50000
#define NE 800000
#define NB ((NN + 1023) / 1024)

typedef __attribute__((ext_vector_type(8))) short short8;
typedef __attribute__((ext_vector_type(4))) float f32x4;

#define AS1 __attribute__((address_space(1)))
#define AS3 __attribute__((address_space(3)))

__device__ inline float bf2f(unsigned short u) {
    unsigned v = (unsigned)u << 16;
    return __builtin_bit_cast(float, v);
}
__device__ inline unsigned short f2bf(float f) {
    return __builtin_bit_cast(unsigned short, __float2bfloat16(f));
}

// ---------------- prep: zero cnt/stats, x->bf16, pack weights (one launch) ----------------
__device__ inline void packw_dev(const float* __restrict__ Wl, const float* __restrict__ Wr,
                                 unsigned short* __restrict__ Wb, int C, int idx) {
    int K = 2 * C;
    if (idx >= 256 * K) return;
    int n = idx / K, k = idx % K;
    float v = (k < C) ? Wl[n * C + k] : Wr[n * C + (k - C)];
    Wb[idx] = f2bf(v);
}

__global__ __launch_bounds__(256) void k_prep(const float* __restrict__ x,
                                              const float* __restrict__ Wl0, const float* __restrict__ Wr0,
                                              const float* __restrict__ Wl1, const float* __restrict__ Wr1,
                                              const float* __restrict__ Wl2, const float* __restrict__ Wr2,
                                              unsigned short* __restrict__ F0,
                                              unsigned short* __restrict__ Wb0,
                                              unsigned short* __restrict__ Wb1,
                                              unsigned short* __restrict__ Wb2,
                                              int* __restrict__ cnt, float* __restrict__ stats) {
    int b = blockIdx.x, t = threadIdx.x;
    if (b < 6250) {  // x fp32 [NN][128] -> F0[:,128:256] bf16
        int i = b * 256 + t;
        if (i < NN * 32) {
            int row = i >> 5, c4 = (i & 31) * 4;
            float4 v = reinterpret_cast<const float4*>(x)[i];
            ushort4 o;
            o.x = f2bf(v.x); o.y = f2bf(v.y); o.z = f2bf(v.z); o.w = f2bf(v.w);
            *reinterpret_cast<ushort4*>(F0 + (size_t)row * 256 + 128 + c4) = o;
        }
        return;
    }
    b -= 6250;
    if (b < 256) { packw_dev(Wl0, Wr0, Wb0, 128, b * 256 + t); return; }
    b -= 256;
    if (b < 512) { packw_dev(Wl1, Wr1, Wb1, 256, b * 256 + t); return; }
    b -= 512;
    if (b < 512) { packw_dev(Wl2, Wr2, Wb2, 256, b * 256 + t); return; }
    b -= 512;
    if (b < 196) { int i = b * 256 + t; if (i < NN) cnt[i] = 0; return; }
    b -= 196;
    if (b < 6) { int i = b * 256 + t; if (i < 1536) stats[i] = 0.f; return; }
}
#define PREP_BLOCKS (6250 + 256 + 512 + 512 + 196 + 6)

// ---------------- CSR build ----------------
__global__ __launch_bounds__(256) void k_count(const int* __restrict__ dst, int* __restrict__ cnt) {
    int e = blockIdx.x * 256 + threadIdx.x;
    if (e < NE) atomicAdd(&cnt[dst[e]], 1);
}

__global__ __launch_bounds__(1024) void k_scanA(const int* __restrict__ cnt, int* __restrict__ row_start,
                                                int* __restrict__ bsum) {
    __shared__ int wsum[16];
    int t = threadIdx.x, lane = t & 63, wid = t >> 6;
    int i = blockIdx.x * 1024 + t;
    int v = (i < NN) ? cnt[i] : 0;
    int x = v;
    #pragma unroll
    for (int off = 1; off < 64; off <<= 1) {
        int y = __shfl_up(x, off, 64);
        if (lane >= off) x += y;
    }
    if (lane == 63) wsum[wid] = x;
    __syncthreads();
    if (t < 16) {
        int s = wsum[t];
        #pragma unroll
        for (int off = 1; off < 16; off <<= 1) {
            int y = __shfl_up(s, off, 16);
            if (t >= off) s += y;
        }
        wsum[t] = s;
    }
    __syncthreads();
    int pre = wid ? wsum[wid - 1] : 0;
    if (i < NN) row_start[i] = pre + x - v;
    if (t == 0) bsum[blockIdx.x] = wsum[15];
}

__global__ __launch_bounds__(64) void k_scanB(const int* __restrict__ bsum, int* __restrict__ boff,
                                              int* __restrict__ row_start) {
    int l = threadIdx.x;
    int v = (l < NB) ? bsum[l] : 0;
    int x = v;
    #pragma unroll
    for (int off = 1; off < 64; off <<= 1) {
        int y = __shfl_up(x, off, 64);
        if (l >= off) x += y;
    }
    boff[l] = x - v;
    if (l == 63) row_start[NN] = x;
}

__global__ __launch_bounds__(1024) void k_scanC(int* __restrict__ row_start, const int* __restrict__ boff,
                                                int* __restrict__ cursor) {
    int i = blockIdx.x * 1024 + threadIdx.x;
    if (i < NN) {
        int rs = row_start[i] + boff[blockIdx.x];
        row_start[i] = rs;
        cursor[i] = rs;
    }
}

__global__ __launch_bounds__(256) void k_scatter(const int* __restrict__ src, const int* __restrict__ dst,
                                                 int* __restrict__ cursor, int* __restrict__ col) {
    int e = blockIdx.x * 256 + threadIdx.x;
    if (e >= NE) return;
    int d = dst[e];
    int p = atomicAdd(&cursor[d], 1);
    col[p] = src[e];
}

// ---------------- mean aggregation: unroll 8, reads F[:,C:], writes F[:,:C] ----------------
template <int C, int S>
__global__ __launch_bounds__(256) void k_agg3(unsigned short* __restrict__ F,
                                              const int* __restrict__ row_start,
                                              const int* __restrict__ col) {
    constexpr int LPN = C / 8;       // lanes per node
    constexpr int NPB = 256 / LPN;   // nodes per block
    int l = threadIdx.x & (LPN - 1);
    int n = blockIdx.x * NPB + (threadIdx.x / LPN);
    if (n >= NN) return;
    int beg = row_start[n], end = row_start[n + 1];
    float inv = 1.0f / (float)((end - beg) > 1 ? (end - beg) : 1);
    float a[8] = {0.f, 0.f, 0.f, 0.f, 0.f, 0.f, 0.f, 0.f};
    const unsigned short* hp = F + C + l * 8;  // h half
    for (int base = beg; base < end; base += LPN) {
        int idx = base + l;
        int my = (idx < end) ? col[idx] : 0;
        int cnt = end - base; if (cnt > LPN) cnt = LPN;
        int j = 0;
        for (; j + 8 <= cnt; j += 8) {
            int s[8];
            #pragma unroll
            for (int q = 0; q < 8; ++q) s[q] = __shfl(my, j + q, LPN);
            short8 v[8];
            #pragma unroll
            for (int q = 0; q < 8; ++q) v[q] = *reinterpret_cast<const short8*>(hp + (size_t)s[q] * S);
            #pragma unroll
            for (int q = 0; q < 8; ++q)
                #pragma unroll
                for (int k = 0; k < 8; ++k) a[k] += bf2f((unsigned short)v[q][k]);
        }
        for (; j + 4 <= cnt; j += 4) {
            int s0 = __shfl(my, j + 0, LPN);
            int s1 = __shfl(my, j + 1, LPN);
            int s2 = __shfl(my, j + 2, LPN);
            int s3 = __shfl(my, j + 3, LPN);
            short8 v0 = *reinterpret_cast<const short8*>(hp + (size_t)s0 * S);
            short8 v1 = *reinterpret_cast<const short8*>(hp + (size_t)s1 * S);
            short8 v2 = *reinterpret_cast<const short8*>(hp + (size_t)s2 * S);
            short8 v3 = *reinterpret_cast<const short8*>(hp + (size_t)s3 * S);
            #pragma unroll
            for (int k = 0; k < 8; ++k) {
                a[k] += bf2f((unsigned short)v0[k]);
                a[k] += bf2f((unsigned short)v1[k]);
                a[k] += bf2f((unsigned short)v2[k]);
                a[k] += bf2f((unsigned short)v3[k]);
            }
        }
        for (; j < cnt; ++j) {
            int s = __shfl(my, j, LPN);
            short8 v = *reinterpret_cast<const short8*>(hp + (size_t)s * S);
            #pragma unroll
            for (int k = 0; k < 8; ++k) a[k] += bf2f((unsigned short)v[k]);
        }
    }
    unsigned short o[8];
    #pragma unroll
    for (int k = 0; k < 8; ++k) o[k] = f2bf(a[k] * inv);
    *reinterpret_cast<short8*>(F + (size_t)n * S + l * 8) = *reinterpret_cast<short8*>(o);
}

// ---------------- barrier-free MFMA GEMM, XCD-affine + asm-pinned DEPTH-4 A ring + setprio ----
template <int K>
__global__ __launch_bounds__(512) void k_gemm10(const unsigned short* __restrict__ F,  // [NN][K]
                                                const unsigned short* __restrict__ Wb, // [256][K]
                                                unsigned short* __restrict__ zb, int ZS, int zoff,
                                                float* __restrict__ st) {
    constexpr int T = K / 32;        // K-steps
    constexpr int SL = K / 8;        // 16B slots per col
    constexpr int LOG_SL = (K == 512) ? 6 : 5;
    __shared__ __attribute__((aligned(16))) unsigned short sB[64 * K];  // >= 32 KB; reused for stats

    // XCD-affine remap: bid in [0,416); hw XCD = bid%8. All 4 tiles of a stripe share an XCD.
    int bid = blockIdx.x;
    int xcd = bid & 7, j = bid >> 3;       // j in [0,52)
    int tile = j & 3;
    int stripe = (j >> 2) * 8 + xcd;       // [0,104)
    if (stripe * 512 >= NN) return;        // dead stripes 98..103

    int tid = threadIdx.x;
    int lane = tid & 63, w = tid >> 6;
    int colB = tile * 64;
    int row0 = stripe * 512 + w * 64;
    int rl = lane & 15, kh = lane >> 4;

    // ---- stage B panel once (XOR-swizzled; linear LDS dest, pre-swizzled source)
    #pragma unroll
    for (int rnd = 0; rnd < (64 * SL) / 512; ++rnd) {
        int u = rnd * 512 + tid;
        int bcol = u >> LOG_SL, s = u & (SL - 1);
        int gk = (s ^ (bcol & 15)) * 8;
        __builtin_amdgcn_global_load_lds((const AS1 void*)(Wb + (size_t)(colB + bcol) * K + gk),
                                         (AS3 void*)(sB + (size_t)(rnd * 512 + w * 64) * 8), 16, 0, 0);
    }
    __syncthreads();  // drains vmcnt to 0 -> ring counting below is exact

    // ---- A row pointers (clamped; clamped rows skipped in epilogue)
    const unsigned short* ap[4];
    #pragma unroll
    for (int m = 0; m < 4; ++m) {
        int r = row0 + m * 16 + rl;
        if (r >= NN) r = NN - 1;
        ap[m] = F + (size_t)r * K + kh * 8;
    }

    f32x4 acc[4][4] = {};
    short8 ring[4][4];  // asm-pinned depth-4 prefetch ring; indices compile-time after unroll

    // prologue: 16 loads in flight (oldest-first order matters for vmcnt counting)
    #pragma unroll
    for (int d = 0; d < 4; ++d)
        #pragma unroll
        for (int m = 0; m < 4; ++m)
            asm volatile("global_load_dwordx4 %0, %1, off"
                         : "=v"(ring[d][m]) : "v"(ap[m] + d * 32));

    #pragma unroll
    for (int t = 0; t < T; ++t) {
        // wait for ring slot t (oldest 4); keep up to 12 newer loads in flight
        if (t + 3 < T)      asm volatile("s_waitcnt vmcnt(12)");
        else if (t + 2 < T) asm volatile("s_waitcnt vmcnt(8)");
        else if (t + 1 < T) asm volatile("s_waitcnt vmcnt(4)");
        else                asm volatile("s_waitcnt vmcnt(0)");
        __builtin_amdgcn_sched_barrier(0);  // rule #18: keep MFMA below the wait

        short8 bf[4];
        int kc = t * 4 + kh;
        #pragma unroll
        for (int n = 0; n < 4; ++n) {
            int c = n * 16 + rl;  // local col
            int unit = (c << LOG_SL) + (kc ^ (c & 15));
            bf[n] = *reinterpret_cast<const short8*>(sB + (size_t)unit * 8);
        }
        __builtin_amdgcn_s_setprio(1);
        #pragma unroll
        for (int m = 0; m < 4; ++m)
            #pragma unroll
            for (int n = 0; n < 4; ++n)
                acc[m][n] = __builtin_amdgcn_mfma_f32_16x16x32_bf16(ring[t % 4][m], bf[n],
                                                                    acc[m][n], 0, 0, 0);
        __builtin_amdgcn_s_setprio(0);
        if (t + 4 < T) {
            #pragma unroll
            for (int m = 0; m < 4; ++m)
                asm volatile("global_load_dwordx4 %0, %1, off"
                             : "=v"(ring[t % 4][m]) : "v"(ap[m] + (t + 4) * 32));
        }
    }

    // ---- epilogue: bf16 store + per-column BN partial sums (fp32)
    int cbase = lane & 15;
    int rbase = (lane >> 4) * 4;
    float s1[4] = {0.f, 0.f, 0.f, 0.f};
    float s2[4] = {0.f, 0.f, 0.f, 0.f};
    #pragma unroll
    for (int m = 0; m < 4; ++m) {
        #pragma unroll
        for (int jj = 0; jj < 4; ++jj) {
            int r = row0 + m * 16 + rbase + jj;
            if (r < NN) {
                #pragma unroll
                for (int n = 0; n < 4; ++n) {
                    float v = acc[m][n][jj];
                    zb[(size_t)r * ZS + zoff + colB + n * 16 + cbase] = f2bf(v);
                    s1[n] += v;
                    s2[n] += v * v;
                }
            }
        }
    }
    // within-wave fold (lanes with same cbase)
    #pragma unroll
    for (int n = 0; n < 4; ++n) {
        s1[n] += __shfl_xor(s1[n], 16);
        s1[n] += __shfl_xor(s1[n], 32);
        s2[n] += __shfl_xor(s2[n], 16);
        s2[n] += __shfl_xor(s2[n], 32);
    }
    // cross-wave fold in LDS (alias sB; all B reads are done), then 1 atomic/address/block
    __syncthreads();
    float* red = (float*)sB;  // 1024 floats = 4 KB << sizeof(sB)
    if (lane < 16) {
        #pragma unroll
        for (int n = 0; n < 4; ++n) {
            red[(w * 4 + n) * 16 + lane] = s1[n];
            red[512 + (w * 4 + n) * 16 + lane] = s2[n];
        }
    }
    __syncthreads();
    if (tid < 128) {
        int stat = tid >> 6, idx = tid & 63;
        int n = idx >> 4, l16 = idx & 15;
        float s = 0.f;
        #pragma unroll
        for (int w2 = 0; w2 < 8; ++w2) s += red[stat * 512 + (w2 * 4 + n) * 16 + l16];
        atomicAdd(&st[stat * 256 + colB + n * 16 + l16], s);
    }
}

// ---------------- BatchNorm apply (BN params computed per-block from stats) ----------------
// in-place BN+ReLU on bf16 z stored at F[:,256:512]
__global__ __launch_bounds__(256) void k_bnip2(unsigned short* __restrict__ F1,
                                               const float* __restrict__ st,
                                               const float* __restrict__ g,
                                               const float* __restrict__ b) {
    __shared__ float ssc[256], ssh[256];
    int t = threadIdx.x;
    {
        float mu = st[t] * (1.0f / NN);
        float var = st[256 + t] * (1.0f / NN) - mu * mu;
        float rstd = rsqrtf(fmaxf(var, 0.f) + 1e-5f);
        float sc = g[t] * rstd;
        ssc[t] = sc;
        ssh[t] = b[t] - mu * sc;
    }
    __syncthreads();
    int i = blockIdx.x * 256 + t;  // NN*64 ushort4 units
    if (i >= NN * 64) return;
    int row = i >> 6, c4 = (i & 63) * 4;
    unsigned short* p = F1 + (size_t)row * 512 + 256 + c4;
    ushort4 v = *reinterpret_cast<const ushort4*>(p);
    float4 sc = *reinterpret_cast<const float4*>(&ssc[c4]);
    float4 sh = *reinterpret_cast<const float4*>(&ssh[c4]);
    ushort4 o;
    o.x = f2bf(fmaxf(bf2f(v.x) * sc.x + sh.x, 0.f));
    o.y = f2bf(fmaxf(bf2f(v.y) * sc.y + sh.y, 0.f));
    o.z = f2bf(fmaxf(bf2f(v.z) * sc.z + sh.z, 0.f));
    o.w = f2bf(fmaxf(bf2f(v.w) * sc.w + sh.w, 0.f));
    *reinterpret_cast<ushort4*>(p) = o;
}

// final BN (no ReLU): bf16 z at F[:,256:512] -> fp32 out
__global__ __launch_bounds__(256) void k_bnf2(const unsigned short* __restrict__ F,
                                              const float* __restrict__ st,
                                              const float* __restrict__ g,
                                              const float* __restrict__ b,
                                              float* __restrict__ out) {
    __shared__ float ssc[256], ssh[256];
    int t = threadIdx.x;
    {
        float mu = st[t] * (1.0f / NN);
        float var = st[256 + t] * (1.0f / NN) - mu * mu;
        float rstd = rsqrtf(fmaxf(var, 0.f) + 1e-5f);
        float sc = g[t] * rstd;
        ssc[t] = sc;
        ssh[t] = b[t] - mu * sc;
    }
    __syncthreads();
    int i = blockIdx.x * 256 + t;
    if (i >= NN * 64) return;
    int row = i >> 6, c4 = (i & 63) * 4;
    ushort4 v = *reinterpret_cast<const ushort4*>(F + (size_t)row * 512 + 256 + c4);
    float4 sc = *reinterpret_cast<const float4*>(&ssc[c4]);
    float4 sh = *reinterpret_cast<const float4*>(&ssh[c4]);
    float4 o;
    o.x = bf2f(v.x) * sc.x + sh.x;
    o.y = bf2f(v.y) * sc.y + sh.y;
    o.z = bf2f(v.z) * sc.z + sh.z;
    o.w = bf2f(v.w) * sc.w + sh.w;
    reinterpret_cast<float4*>(out)[i] = o;
}

extern "C" void kernel_launch(void* const* d_in, const int* in_sizes, int n_in,
                              void* d_out, int out_size, void* d_ws, size_t ws_size,
                              hipStream_t stream) {
    const float* x   = (const float*)d_in[0];
    const int*   ei  = (const int*)d_in[1];
    const float* Wl0 = (const float*)d_in[2];
    const float* Wr0 = (const float*)d_in[4];
    const float* g0  = (const float*)d_in[5];
    const float* b0  = (const float*)d_in[6];
    const float* Wl1 = (const float*)d_in[7];
    const float* Wr1 = (const float*)d_in[9];
    const float* g1  = (const float*)d_in[10];
    const float* b1  = (const float*)d_in[11];
    const float* Wl2 = (const float*)d_in[12];
    const float* Wr2 = (const float*)d_in[14];
    const float* g2  = (const float*)d_in[15];
    const float* b2  = (const float*)d_in[16];
    float* out = (float*)d_out;

    char* ws = (char*)d_ws;
    size_t off = 0;
    auto alloc = [&](size_t bytes) -> void* {
        void* p = ws + off;
        off = (off + bytes + 255) & ~(size_t)255;
        return p;
    };
    unsigned short* F0 = (unsigned short*)alloc((size_t)NN * 256 * 2);  // layer0 [mean0|x]
    unsigned short* FA = (unsigned short*)alloc((size_t)NN * 512 * 2);  // ping [mean|h]
    unsigned short* FB = (unsigned short*)alloc((size_t)NN * 512 * 2);  // pong [mean|h]
    int*   cnt       = (int*)alloc((size_t)NN * 4);
    int*   cursor    = (int*)alloc((size_t)NN * 4);
    int*   row_start = (int*)alloc((size_t)(NN + 1) * 4);
    int*   col       = (int*)alloc((size_t)NE * 4);
    int*   bsum      = (int*)alloc(64 * 4);
    int*   boff      = (int*)alloc(64 * 4);
    float* stats     = (float*)alloc(3 * 512 * 4);
    unsigned short* Wb0 = (unsigned short*)alloc((size_t)256 * 256 * 2);
    unsigned short* Wb1 = (unsigned short*)alloc((size_t)256 * 512 * 2);
    unsigned short* Wb2 = (unsigned short*)alloc((size_t)256 * 512 * 2);

    // prep (zero cnt/stats, convert x, pack weights) + CSR build
    k_prep<<<PREP_BLOCKS, 256, 0, stream>>>(x, Wl0, Wr0, Wl1, Wr1, Wl2, Wr2,
                                            F0, Wb0, Wb1, Wb2, cnt, stats);
    k_count<<<(NE + 255) / 256, 256, 0, stream>>>(ei + NE, cnt);
    k_scanA<<<NB, 1024, 0, stream>>>(cnt, row_start, bsum);
    k_scanB<<<1, 64, 0, stream>>>(bsum, boff, row_start);
    k_scanC<<<NB, 1024, 0, stream>>>(row_start, boff, cursor);
    k_scatter<<<(NE + 255) / 256, 256, 0, stream>>>(ei, ei + NE, cursor, col);

    const int GGRID = 416;  // 104 stripes x 4 tiles of 64 cols, XCD-affine (stripes 98..103 dead)

    // ---- Layer 0 (C=128, K=256): F0 -> z0 in FA[:,256:] ----
    k_agg3<128, 256><<<(NN + 15) / 16, 256, 0, stream>>>(F0, row_start, col);
    k_gemm10<256><<<GGRID, 512, 0, stream>>>(F0, Wb0, FA, 512, 256, stats);
    k_bnip2<<<12500, 256, 0, stream>>>(FA, stats, g0, b0);

    // ---- Layer 1 (C=256, K=512): FA -> z1 in FB[:,256:] (out-of-place) ----
    k_agg3<256, 512><<<(NN + 7) / 8, 256, 0, stream>>>(FA, row_start, col);
    k_gemm10<512><<<GGRID, 512, 0, stream>>>(FA, Wb1, FB, 512, 256, stats + 512);
    k_bnip2<<<12500, 256, 0, stream>>>(FB, stats + 512, g1, b1);

    // ---- Layer 2 (C=256, K=512): FB -> z2 in FA[:,256:] (FA dead, out-of-place) ----
    k_agg3<256, 512><<<(NN + 7) / 8, 256, 0, stream>>>(FB, row_start, col);
    k_gemm10<512><<<GGRID, 512, 0, stream>>>(FB, Wb2, FA, 512, 256, stats + 1024);
    k_bnf2<<<12500, 256, 0, stream>>>(FA, stats + 1024, g2, b2, out);
}